// Round 1
// baseline (1881.762 us; speedup 1.0000x reference)
//
#include <hip/hip_runtime.h>
#include <hip/hip_bf16.h>

// Problem constants
constexpr int IN_ = 256, H_ = 128, HN_ = 4;
constexpr int S_ = 5, B_ = 1024, M_ = 16, D_ = 512;

__device__ __forceinline__ float lrelu(float z) { return z >= 0.f ? z : 0.2f * z; }

// C[16][128] = act(A[16][K] @ W[128][K]^T + bias)
// A, C in LDS; W global (L2-cached). 256 threads: o = t&127, rows (t>>7)*8..+7.
template<int K, int ACT>
__device__ __forceinline__ void mm16(const float* __restrict__ W,
                                     const float* __restrict__ bias,
                                     const float* A, float* C, int t)
{
    const int o = t & 127;
    const int rbase = (t >> 7) * 8;
    float acc[8] = {0.f, 0.f, 0.f, 0.f, 0.f, 0.f, 0.f, 0.f};
    const float* wrow = W + (size_t)o * K;
    const float* arow = A + rbase * K;
    for (int i = 0; i < K; i += 4) {
        const float4 w4 = *(const float4*)(wrow + i);
#pragma unroll
        for (int j = 0; j < 8; ++j) {
            const float4 a4 = *(const float4*)(arow + j * K + i);
            acc[j] += w4.x * a4.x + w4.y * a4.y + w4.z * a4.z + w4.w * a4.w;
        }
    }
    const float bv = bias ? bias[o] : 0.f;
#pragma unroll
    for (int j = 0; j < 8; ++j) {
        float v = acc[j] + bv;
        if (ACT) v = lrelu(v);
        C[(rbase + j) * 128 + o] = v;
    }
}

// ---------------- K1: target-side chain -> x_sh, wh2 ----------------
__global__ __launch_bounds__(256) void k_target(
    const float* __restrict__ x, const int* __restrict__ tgt,
    const float* __restrict__ fc_w, const float* __restrict__ fc_b,
    const float* __restrict__ q_w, const float* __restrict__ q_b,
    const float* __restrict__ a2w, const float* __restrict__ a2b,
    const float* __restrict__ aW,
    float* __restrict__ x_sh, float* __restrict__ wh2)
{
    const int t = threadIdx.x;
    const int b0 = blockIdx.x * 16;
    const int h = blockIdx.y, s = blockIdx.z;
    const int km = (s < 2) ? 0 : 1;
    const int sh = s * HN_ + h;
    const int kh = km * HN_ + h;

    __shared__ float txs[16 * IN_];
    __shared__ float xs[16 * H_];
    __shared__ float qs[16 * H_];
    __shared__ float h2s[16 * H_];
    __shared__ int tld[16];

    if (t < 16) tld[t] = tgt[b0 + t];
    __syncthreads();

    for (int idx = t; idx < 16 * 64; idx += 256) {
        int r = idx >> 6, c = idx & 63;
        ((float4*)txs)[idx] = *(const float4*)(x + (size_t)tld[r] * IN_ + c * 4);
    }
    __syncthreads();

    mm16<IN_, 1>(fc_w + (size_t)sh * H_ * IN_, fc_b + sh * H_, txs, xs, t);
    __syncthreads();

    // store x_sh (read-only users below, no hazard)
    for (int idx = t; idx < 16 * H_; idx += 256) {
        int r = idx >> 7, o = idx & 127;
        x_sh[((size_t)sh * B_ + b0 + r) * H_ + o] = xs[idx];
    }
    mm16<H_, 0>(q_w + (size_t)sh * H_ * H_, q_b + sh * H_, xs, qs, t);
    __syncthreads();
    mm16<H_, 1>(a2w + (size_t)kh * H_ * H_, a2b + kh * H_, qs, h2s, t);
    __syncthreads();

    // wh2[b,i] = sum_j aW[i,j] * h2[b,j]  -> straight to global
    {
        const int o = t & 127, rbase = (t >> 7) * 8;
        float acc[8] = {0.f, 0.f, 0.f, 0.f, 0.f, 0.f, 0.f, 0.f};
        const float* wrow = aW + (size_t)kh * H_ * H_ + (size_t)o * H_;
        const float* arow = h2s + rbase * H_;
        for (int i = 0; i < H_; i += 4) {
            float4 w4 = *(const float4*)(wrow + i);
#pragma unroll
            for (int j = 0; j < 8; ++j) {
                float4 a4 = *(const float4*)(arow + j * H_ + i);
                acc[j] += w4.x * a4.x + w4.y * a4.y + w4.z * a4.z + w4.w * a4.w;
            }
        }
#pragma unroll
        for (int j = 0; j < 8; ++j)
            wh2[((size_t)sh * B_ + b0 + rbase + j) * H_ + o] = acc[j];
    }
}

// ---------------- K2: neighbor pipeline -> out_sbd ----------------
__global__ __launch_bounds__(256) void k_neighbor(
    const float* __restrict__ x, const int* __restrict__ nbr,
    const float* __restrict__ fc_w, const float* __restrict__ fc_b,
    const float* __restrict__ k_w, const float* __restrict__ k_b,
    const float* __restrict__ v_w, const float* __restrict__ v_b,
    const float* __restrict__ a1w, const float* __restrict__ a1b,
    const float* __restrict__ x_sh, const float* __restrict__ wh2,
    float* __restrict__ out_sbd)
{
    const int t = threadIdx.x;
    const int b = blockIdx.x, h = blockIdx.y, s = blockIdx.z;
    const int km = (s < 2) ? 0 : 1;
    const int sh = s * HN_ + h, kh = km * HN_ + h;

    __shared__ float nys[M_ * IN_];   // 16 KB
    __shared__ float ys[M_ * H_];     // 8 KB
    __shared__ float ks_[M_ * H_];
    __shared__ float vs[M_ * H_];
    __shared__ float h1s[M_ * H_];
    __shared__ float wh2s[H_];
    __shared__ int tld[M_];
    __shared__ float watt[M_], esm[M_];

    if (t < M_) tld[t] = nbr[((size_t)s * B_ + b) * M_ + t];
    if (t >= 128 && t < 256) wh2s[t - 128] = wh2[((size_t)sh * B_ + b) * H_ + (t - 128)];
    __syncthreads();

    for (int idx = t; idx < M_ * 64; idx += 256) {
        int r = idx >> 6, c = idx & 63;
        ((float4*)nys)[idx] = *(const float4*)(x + (size_t)tld[r] * IN_ + c * 4);
    }
    __syncthreads();

    mm16<IN_, 1>(fc_w + (size_t)sh * H_ * IN_, fc_b + sh * H_, nys, ys, t);
    __syncthreads();
    mm16<H_, 0>(k_w + (size_t)sh * H_ * H_, k_b + sh * H_, ys, ks_, t);
    mm16<H_, 0>(v_w + (size_t)sh * H_ * H_, v_b + sh * H_, ys, vs, t);
    __syncthreads();
    mm16<H_, 1>(a1w + (size_t)kh * H_ * H_, a1b + kh * H_, ks_, h1s, t);
    __syncthreads();

    // att[m] = h1[m] . wh2
    {
        int m = t >> 4, l = t & 15;
        float p = 0.f;
#pragma unroll
        for (int u = 0; u < 8; ++u) p += h1s[m * H_ + l + u * 16] * wh2s[l + u * 16];
        p += __shfl_xor(p, 1);
        p += __shfl_xor(p, 2);
        p += __shfl_xor(p, 4);
        p += __shfl_xor(p, 8);
        if (l == 0) watt[m] = p;
    }
    __syncthreads();

    if (t == 0) {
        float mx = watt[0];
        for (int m = 1; m < M_; ++m) mx = fmaxf(mx, watt[m]);
        float sum = 0.f;
        for (int m = 0; m < M_; ++m) { float e = expf(watt[m] - mx); esm[m] = e; sum += e; }
        float inv = 1.f / sum;
        for (int m = 0; m < M_; ++m) esm[m] *= inv;
    }
    __syncthreads();

    if (t < H_) {
        float acc = 0.f;
#pragma unroll
        for (int m = 0; m < M_; ++m) acc += lrelu(vs[m * H_ + t] * esm[m]);
        float xv = x_sh[((size_t)sh * B_ + b) * H_ + t];
        out_sbd[((size_t)s * B_ + b) * D_ + h * H_ + t] = (xv + acc) * 0.5f;
    }
}

// ---------------- K3: fused inner + between semantic attention ----------------
__global__ __launch_bounds__(256) void k_semantic(
    const float* __restrict__ out_sbd,
    const float* __restrict__ ip1w, const float* __restrict__ ip1b,
    const float* __restrict__ ip2w,
    const float* __restrict__ bp1w, const float* __restrict__ bp1b,
    const float* __restrict__ bp2w,
    float* __restrict__ out)
{
    const int b = blockIdx.x, t = threadIdx.x;
    __shared__ float zs[S_ * D_];   // 10 KB
    __shared__ float mps[2 * D_];   // 4 KB
    __shared__ float red[128];
    __shared__ float svals[3];
    __shared__ float beta_s[3];

    for (int idx = t; idx < S_ * D_ / 4; idx += 256) {
        int sidx = idx >> 7, c = idx & 127;
        ((float4*)zs)[idx] = ((const float4*)(out_sbd + ((size_t)sidx * B_ + b) * D_))[c];
    }
    __syncthreads();

    // inner semantic attention per metapath
    for (int ki = 0; ki < 2; ++ki) {
        const int s0 = (ki == 0) ? 0 : 2;
        const int P = (ki == 0) ? 2 : 3;
        for (int p = 0; p < P; ++p) {
            if (t < H_) {
                const float* wrow = ip1w + ((size_t)ki * H_ + t) * D_;
                const float* zrow = zs + (s0 + p) * D_;
                float acc = 0.f;
                for (int d = 0; d < D_; d += 4) {
                    float4 w4 = *(const float4*)(wrow + d);
                    float4 z4 = *(const float4*)(zrow + d);
                    acc += w4.x * z4.x + w4.y * z4.y + w4.z * z4.z + w4.w * z4.w;
                }
                float wv = tanhf(acc + ip1b[ki * H_ + t]);
                red[t] = wv * ip2w[ki * H_ + t];
            }
            __syncthreads();
            if (t == 0) {
                float ssum = 0.f;
                for (int i = 0; i < H_; ++i) ssum += red[i];
                svals[p] = ssum;
            }
            __syncthreads();
        }
        if (t == 0) {
            float mx = svals[0];
            for (int p = 1; p < P; ++p) mx = fmaxf(mx, svals[p]);
            float sum = 0.f;
            for (int p = 0; p < P; ++p) { float e = expf(svals[p] - mx); beta_s[p] = e; sum += e; }
            for (int p = 0; p < P; ++p) beta_s[p] /= sum;
        }
        __syncthreads();
        for (int d = t; d < D_; d += 256) {
            float acc = 0.f;
            for (int p = 0; p < P; ++p) acc += beta_s[p] * zs[(s0 + p) * D_ + d];
            mps[ki * D_ + d] = acc;
        }
        __syncthreads();
    }

    // between semantic attention
    for (int p = 0; p < 2; ++p) {
        if (t < H_) {
            const float* wrow = bp1w + (size_t)t * D_;
            const float* zrow = mps + p * D_;
            float acc = 0.f;
            for (int d = 0; d < D_; d += 4) {
                float4 w4 = *(const float4*)(wrow + d);
                float4 z4 = *(const float4*)(zrow + d);
                acc += w4.x * z4.x + w4.y * z4.y + w4.z * z4.z + w4.w * z4.w;
            }
            float wv = tanhf(acc + bp1b[t]);
            red[t] = wv * bp2w[t];
        }
        __syncthreads();
        if (t == 0) {
            float ssum = 0.f;
            for (int i = 0; i < H_; ++i) ssum += red[i];
            svals[p] = ssum;
        }
        __syncthreads();
    }
    if (t == 0) {
        float mx = fmaxf(svals[0], svals[1]);
        float e0 = expf(svals[0] - mx), e1 = expf(svals[1] - mx);
        float inv = 1.f / (e0 + e1);
        beta_s[0] = e0 * inv; beta_s[1] = e1 * inv;
    }
    __syncthreads();
    for (int d = t; d < D_; d += 256)
        out[(size_t)b * D_ + d] = beta_s[0] * mps[d] + beta_s[1] * mps[D_ + d];
}

extern "C" void kernel_launch(void* const* d_in, const int* in_sizes, int n_in,
                              void* d_out, int out_size, void* d_ws, size_t ws_size,
                              hipStream_t stream)
{
    const float* x    = (const float*)d_in[0];
    const int*   tgt  = (const int*)d_in[1];
    const int*   nbr  = (const int*)d_in[2];
    const float* fc_w = (const float*)d_in[3];
    const float* fc_b = (const float*)d_in[4];
    const float* q_w  = (const float*)d_in[5];
    const float* q_b  = (const float*)d_in[6];
    const float* k_w  = (const float*)d_in[7];
    const float* k_b  = (const float*)d_in[8];
    const float* v_w  = (const float*)d_in[9];
    const float* v_b  = (const float*)d_in[10];
    const float* attW = (const float*)d_in[11];
    const float* a1w  = (const float*)d_in[12];
    const float* a1b  = (const float*)d_in[13];
    const float* a2w  = (const float*)d_in[14];
    const float* a2b  = (const float*)d_in[15];
    const float* ip1w = (const float*)d_in[16];
    const float* ip1b = (const float*)d_in[17];
    const float* ip2w = (const float*)d_in[18];
    const float* bp1w = (const float*)d_in[19];
    const float* bp1b = (const float*)d_in[20];
    const float* bp2w = (const float*)d_in[21];

    float* out = (float*)d_out;
    float* ws  = (float*)d_ws;

    const size_t SZ1 = (size_t)S_ * HN_ * B_ * H_;   // 2,621,440 floats
    float* x_sh    = ws;
    float* wh2     = x_sh + SZ1;
    float* out_sbd = wh2 + SZ1;                      // [S][B][D]

    k_target<<<dim3(B_ / 16, HN_, S_), 256, 0, stream>>>(
        x, tgt, fc_w, fc_b, q_w, q_b, a2w, a2b, attW, x_sh, wh2);
    k_neighbor<<<dim3(B_, HN_, S_), 256, 0, stream>>>(
        x, nbr, fc_w, fc_b, k_w, k_b, v_w, v_b, a1w, a1b, x_sh, wh2, out_sbd);
    k_semantic<<<dim3(B_), 256, 0, stream>>>(
        out_sbd, ip1w, ip1b, ip2w, bp1w, bp1b, bp2w, out);
}

// Round 4
// 763.849 us; speedup vs baseline: 2.4635x; 2.4635x over previous
//
#include <hip/hip_runtime.h>
#include <hip/hip_bf16.h>

constexpr int IN_ = 256, H_ = 128, HN_ = 4;
constexpr int S_ = 5, B_ = 1024, M_ = 16, D_ = 512;

typedef __attribute__((ext_vector_type(8))) short bf16x8;
typedef __attribute__((ext_vector_type(4))) float f32x4;
typedef __attribute__((ext_vector_type(4))) short s16x4;

__device__ __forceinline__ float lrelu(float z) { return z >= 0.f ? z : 0.2f * z; }
__device__ __forceinline__ short f2b(float f) {            // RNE f32->bf16
    unsigned u = __float_as_uint(f);
    u += 0x7FFF + ((u >> 16) & 1);
    return (short)(u >> 16);
}
__device__ __forceinline__ float b2f(short s) {
    return __uint_as_float(((unsigned)(unsigned short)s) << 16);
}

// ---- per-wave 16xK @ Kx128 GEMM via mfma_f32_16x16x32_bf16 ----
// A: LDS, 16 rows of K shorts, XOR-swizzled (granule 8 shorts, key row&7).
// W: global bf16 [128][K] (B-frag B[k][n] = W[n][k] -> contiguous 16B/lane).
// C: 16x128, + bias, optional lrelu; to LDS (swizzled, stride 128) and/or global bf16.
template<int K, int ACT, bool TLDS, bool TGLB>
__device__ __forceinline__ void wave_gemm(
    const short* A, const short* __restrict__ W, const float* __restrict__ bias,
    short* C_lds, short* __restrict__ C_glob, int lane)
{
    f32x4 acc[8];
#pragma unroll
    for (int i = 0; i < 8; ++i) acc[i] = (f32x4){0.f, 0.f, 0.f, 0.f};
    const int m16 = lane & 15;
    const int kg  = (lane >> 4) * 8;          // k-subgroup base
    const short* Ab = A + m16 * K;
    const int aswz = (m16 & 7) << 3;
#pragma unroll
    for (int kk = 0; kk < K; kk += 32) {
        bf16x8 af = *(const bf16x8*)(Ab + ((kk + kg) ^ aswz));
        const short* Wb = W + (size_t)m16 * K + kk + kg;
#pragma unroll
        for (int cb = 0; cb < 8; ++cb) {
            bf16x8 bf = *(const bf16x8*)(Wb + (size_t)cb * 16 * K);
            acc[cb] = __builtin_amdgcn_mfma_f32_16x16x32_bf16(af, bf, acc[cb], 0, 0, 0);
        }
    }
    const int r0 = (lane >> 4) * 4;           // C/D: col=lane&15, row=(lane>>4)*4+i
#pragma unroll
    for (int cb = 0; cb < 8; ++cb) {
        const int col = cb * 16 + m16;
        const float bv = bias ? bias[col] : 0.f;
#pragma unroll
        for (int i = 0; i < 4; ++i) {
            const int r = r0 + i;
            float v = acc[cb][i] + bv;
            if (ACT) v = lrelu(v);
            const short bs = f2b(v);
            if (TLDS) C_lds[r * H_ + (col ^ ((r & 7) << 3))] = bs;
            if (TGLB) C_glob[(size_t)r * H_ + col] = bs;
        }
    }
}

// ---- f32->bf16 weight conversion (7 tensors), blockIdx.y selects tensor ----
// CORRECT element counts: fc_w (S,HN,H,IN)=655360; q/k/v (S,HN,H,H)=327680;
// att_W/fc1/fc2 (K,HN,H,H)=131072.
__global__ __launch_bounds__(256) void k_convert(
    const float* f0, const float* f1, const float* f2, const float* f3,
    const float* f4, const float* f5, const float* f6,
    short* g0, short* g1, short* g2, short* g3, short* g4, short* g5, short* g6)
{
    const float* s; short* d; int n;
    switch (blockIdx.y) {
        case 0: s = f0; d = g0; n = 655360; break;
        case 1: s = f1; d = g1; n = 327680; break;
        case 2: s = f2; d = g2; n = 327680; break;
        case 3: s = f3; d = g3; n = 327680; break;
        case 4: s = f4; d = g4; n = 131072; break;
        case 5: s = f5; d = g5; n = 131072; break;
        default: s = f6; d = g6; n = 131072; break;
    }
    int i = (blockIdx.x * 256 + threadIdx.x) * 4;
    if (i >= n) return;
    float4 v = *(const float4*)(s + i);
    s16x4 p; p.x = f2b(v.x); p.y = f2b(v.y); p.z = f2b(v.z); p.w = f2b(v.w);
    *(s16x4*)(d + i) = p;
}

// ---- K1: target chain (fc->q->a2->aW) -> x_shb, wh2b (bf16) ----
__global__ __launch_bounds__(256) void k_target(
    const float* __restrict__ x, const int* __restrict__ tgt,
    const short* __restrict__ wb_fc, const float* __restrict__ fc_b,
    const short* __restrict__ wb_q,  const float* __restrict__ q_b,
    const short* __restrict__ wb_a2, const float* __restrict__ a2_b,
    const short* __restrict__ wb_aW,
    short* __restrict__ x_shb, short* __restrict__ wh2b)
{
    const int t = threadIdx.x, lane = t & 63, w = t >> 6;
    const int bt = blockIdx.x, h = blockIdx.y, s = blockIdx.z;
    const int km = (s < 2) ? 0 : 1;
    const int sh = s * HN_ + h, kh = km * HN_ + h;
    const int b0w = bt * 64 + w * 16;          // this wave's 16 target rows

    __shared__ __align__(16) short A0[4 * 16 * IN_];   // 32 KB
    __shared__ __align__(16) short Y[4 * 16 * H_];     // 16 KB
    short* A0w = A0 + w * (16 * IN_);
    short* Y1w = Y + w * (16 * H_);
    short* Qw  = A0w;                 // reuse after G1
    short* H2w = A0w + 16 * H_;

    // gather 16 target rows (f32 -> bf16, swizzled)
    for (int m = 0; m < 16; ++m) {
        const int g = tgt[b0w + m];
        float4 v = *(const float4*)(x + (size_t)g * IN_ + lane * 4);
        s16x4 p; p.x = f2b(v.x); p.y = f2b(v.y); p.z = f2b(v.z); p.w = f2b(v.w);
        const int off = (lane * 4) ^ ((m & 7) << 3);
        *(s16x4*)(A0w + m * IN_ + off) = p;
    }
    __syncthreads();
    wave_gemm<IN_, 1, true, true>(A0w, wb_fc + (size_t)sh * H_ * IN_, fc_b + sh * H_,
                                  Y1w, x_shb + ((size_t)sh * B_ + b0w) * H_, lane);
    __syncthreads();
    wave_gemm<H_, 0, true, false>(Y1w, wb_q + (size_t)sh * H_ * H_, q_b + sh * H_,
                                  Qw, nullptr, lane);
    __syncthreads();
    wave_gemm<H_, 1, true, false>(Qw, wb_a2 + (size_t)kh * H_ * H_, a2_b + kh * H_,
                                  H2w, nullptr, lane);
    __syncthreads();
    wave_gemm<H_, 0, false, true>(H2w, wb_aW + (size_t)kh * H_ * H_, nullptr,
                                  nullptr, wh2b + ((size_t)sh * B_ + b0w) * H_, lane);
}

// ---- K2: neighbor pipeline (fc->k/v->a1->scores->softmax->merge) -> out_sbd ----
__global__ __launch_bounds__(256) void k_neighbor(
    const float* __restrict__ x, const int* __restrict__ nbr,
    const short* __restrict__ wb_fc, const float* __restrict__ fc_b,
    const short* __restrict__ wb_k,  const float* __restrict__ k_b,
    const short* __restrict__ wb_v,  const float* __restrict__ v_b,
    const short* __restrict__ wb_a1, const float* __restrict__ a1_b,
    const short* __restrict__ x_shb, const short* __restrict__ wh2b,
    float* __restrict__ out_sbd)
{
    const int t = threadIdx.x, lane = t & 63, w = t >> 6;
    const int bt = blockIdx.x, h = blockIdx.y, s = blockIdx.z;
    const int km = (s < 2) ? 0 : 1;
    const int sh = s * HN_ + h, kh = km * HN_ + h;
    const int b = bt * 4 + w;                 // this wave's target node

    __shared__ __align__(16) short A0[4 * 16 * IN_];   // 32 KB
    __shared__ __align__(16) short Y[4 * 16 * H_];     // 16 KB
    short* A0w = A0 + w * (16 * IN_);
    short* Yw  = Y + w * (16 * H_);
    short* Khw = A0w;                 // reuse after G1
    short* Vhw = A0w + 16 * H_;
    short* H1w = Yw;                  // reuse after G2/G3

    // gather 16 neighbor rows
    for (int m = 0; m < 16; ++m) {
        const int g = nbr[((size_t)s * B_ + b) * M_ + m];
        float4 v = *(const float4*)(x + (size_t)g * IN_ + lane * 4);
        s16x4 p; p.x = f2b(v.x); p.y = f2b(v.y); p.z = f2b(v.z); p.w = f2b(v.w);
        const int off = (lane * 4) ^ ((m & 7) << 3);
        *(s16x4*)(A0w + m * IN_ + off) = p;
    }
    __syncthreads();
    // G1: y = lrelu(fc(ny))
    wave_gemm<IN_, 1, true, false>(A0w, wb_fc + (size_t)sh * H_ * IN_, fc_b + sh * H_,
                                   Yw, nullptr, lane);
    __syncthreads();
    // G2: kh = k(y) ; G3: vh = v(y)
    wave_gemm<H_, 0, true, false>(Yw, wb_k + (size_t)sh * H_ * H_, k_b + sh * H_,
                                  Khw, nullptr, lane);
    wave_gemm<H_, 0, true, false>(Yw, wb_v + (size_t)sh * H_ * H_, v_b + sh * H_,
                                  Vhw, nullptr, lane);
    __syncthreads();
    // G4: h1 = lrelu(a1(kh))
    wave_gemm<H_, 1, true, false>(Khw, wb_a1 + (size_t)kh * H_ * H_, a1_b + kh * H_,
                                  H1w, nullptr, lane);
    __syncthreads();

    // scores: att[m] = h1[m] . wh2[b]   (lane l: m=l>>2, quarter p=l&3)
    const short* wrow = wh2b + ((size_t)sh * B_ + b) * H_;
    const int m = lane >> 2, p = lane & 3;
    const int sw = (m & 7) << 3;
    float sc = 0.f;
#pragma unroll
    for (int j = 0; j < 32; ++j) {
        const int d = p * 32 + j;
        sc += b2f(H1w[m * H_ + (d ^ sw)]) * b2f(wrow[d]);
    }
    sc += __shfl_xor(sc, 1);
    sc += __shfl_xor(sc, 2);
    // softmax over 16 neighbors (redundant per lane, all-register)
    float e[16];
    float mx = -1e30f;
#pragma unroll
    for (int mm = 0; mm < 16; ++mm) { e[mm] = __shfl(sc, mm * 4); mx = fmaxf(mx, e[mm]); }
    float ssum = 0.f;
#pragma unroll
    for (int mm = 0; mm < 16; ++mm) { e[mm] = expf(e[mm] - mx); ssum += e[mm]; }
    const float inv = 1.f / ssum;

    // out = (x_sh + sum_m lrelu(vh*e)) * 0.5
    const short* xrow = x_shb + ((size_t)sh * B_ + b) * H_;
    float* orow = out_sbd + ((size_t)s * B_ + b) * D_ + h * H_;
#pragma unroll
    for (int rep = 0; rep < 2; ++rep) {
        const int d = rep * 64 + lane;
        float hacc = 0.f;
#pragma unroll
        for (int mm = 0; mm < 16; ++mm) {
            const float vv = b2f(Vhw[mm * H_ + (d ^ ((mm & 7) << 3))]);
            hacc += lrelu(vv * (e[mm] * inv));
        }
        orow[d] = (b2f(xrow[d]) + hacc) * 0.5f;
    }
}

// ---- K3: fused inner + between semantic attention (f32) ----
__global__ __launch_bounds__(256) void k_semantic(
    const float* __restrict__ out_sbd,
    const float* __restrict__ ip1w, const float* __restrict__ ip1b,
    const float* __restrict__ ip2w,
    const float* __restrict__ bp1w, const float* __restrict__ bp1b,
    const float* __restrict__ bp2w,
    float* __restrict__ out)
{
    const int b = blockIdx.x, t = threadIdx.x;
    __shared__ float zs[S_ * D_];
    __shared__ float mps[2 * D_];
    __shared__ float red[128];
    __shared__ float svals[3];
    __shared__ float beta_s[3];

    for (int idx = t; idx < S_ * D_ / 4; idx += 256) {
        int sidx = idx >> 7, c = idx & 127;
        ((float4*)zs)[idx] = ((const float4*)(out_sbd + ((size_t)sidx * B_ + b) * D_))[c];
    }
    __syncthreads();

    for (int ki = 0; ki < 2; ++ki) {
        const int s0 = (ki == 0) ? 0 : 2;
        const int P = (ki == 0) ? 2 : 3;
        for (int p = 0; p < P; ++p) {
            if (t < H_) {
                const float* wrow = ip1w + ((size_t)ki * H_ + t) * D_;
                const float* zrow = zs + (s0 + p) * D_;
                float acc = 0.f;
                for (int d = 0; d < D_; d += 4) {
                    float4 w4 = *(const float4*)(wrow + d);
                    float4 z4 = *(const float4*)(zrow + d);
                    acc += w4.x * z4.x + w4.y * z4.y + w4.z * z4.z + w4.w * z4.w;
                }
                red[t] = tanhf(acc + ip1b[ki * H_ + t]) * ip2w[ki * H_ + t];
            }
            __syncthreads();
            if (t == 0) {
                float ssum = 0.f;
                for (int i = 0; i < H_; ++i) ssum += red[i];
                svals[p] = ssum;
            }
            __syncthreads();
        }
        if (t == 0) {
            float mx = svals[0];
            for (int p = 1; p < P; ++p) mx = fmaxf(mx, svals[p]);
            float sum = 0.f;
            for (int p = 0; p < P; ++p) { float e = expf(svals[p] - mx); beta_s[p] = e; sum += e; }
            for (int p = 0; p < P; ++p) beta_s[p] /= sum;
        }
        __syncthreads();
        for (int d = t; d < D_; d += 256) {
            float acc = 0.f;
            for (int p = 0; p < P; ++p) acc += beta_s[p] * zs[(s0 + p) * D_ + d];
            mps[ki * D_ + d] = acc;
        }
        __syncthreads();
    }

    for (int p = 0; p < 2; ++p) {
        if (t < H_) {
            const float* wrow = bp1w + (size_t)t * D_;
            const float* zrow = mps + p * D_;
            float acc = 0.f;
            for (int d = 0; d < D_; d += 4) {
                float4 w4 = *(const float4*)(wrow + d);
                float4 z4 = *(const float4*)(zrow + d);
                acc += w4.x * z4.x + w4.y * z4.y + w4.z * z4.z + w4.w * z4.w;
            }
            red[t] = tanhf(acc + bp1b[t]) * bp2w[t];
        }
        __syncthreads();
        if (t == 0) {
            float ssum = 0.f;
            for (int i = 0; i < H_; ++i) ssum += red[i];
            svals[p] = ssum;
        }
        __syncthreads();
    }
    if (t == 0) {
        float mx = fmaxf(svals[0], svals[1]);
        float e0 = expf(svals[0] - mx), e1 = expf(svals[1] - mx);
        float inv = 1.f / (e0 + e1);
        beta_s[0] = e0 * inv; beta_s[1] = e1 * inv;
    }
    __syncthreads();
    for (int d = t; d < D_; d += 256)
        out[(size_t)b * D_ + d] = beta_s[0] * mps[d] + beta_s[1] * mps[D_ + d];
}

extern "C" void kernel_launch(void* const* d_in, const int* in_sizes, int n_in,
                              void* d_out, int out_size, void* d_ws, size_t ws_size,
                              hipStream_t stream)
{
    const float* x    = (const float*)d_in[0];
    const int*   tgt  = (const int*)d_in[1];
    const int*   nbr  = (const int*)d_in[2];
    const float* fc_w = (const float*)d_in[3];
    const float* fc_b = (const float*)d_in[4];
    const float* q_w  = (const float*)d_in[5];
    const float* q_b  = (const float*)d_in[6];
    const float* k_w  = (const float*)d_in[7];
    const float* k_b  = (const float*)d_in[8];
    const float* v_w  = (const float*)d_in[9];
    const float* v_b  = (const float*)d_in[10];
    const float* attW = (const float*)d_in[11];
    const float* a1w  = (const float*)d_in[12];
    const float* a1b  = (const float*)d_in[13];
    const float* a2w  = (const float*)d_in[14];
    const float* a2b  = (const float*)d_in[15];
    const float* ip1w = (const float*)d_in[16];
    const float* ip1b = (const float*)d_in[17];
    const float* ip2w = (const float*)d_in[18];
    const float* bp1w = (const float*)d_in[19];
    const float* bp1b = (const float*)d_in[20];
    const float* bp2w = (const float*)d_in[21];

    float* out = (float*)d_out;

    // ws layout (shorts unless noted) — TRUE weight sizes
    short* wb_fc = (short*)d_ws;               // 655,360  (S,HN,H,IN)
    short* wb_q  = wb_fc + 655360;             // 327,680  (S,HN,H,H)
    short* wb_k  = wb_q + 327680;
    short* wb_v  = wb_k + 327680;
    short* wb_aW = wb_v + 327680;              // 131,072  (K,HN,H,H)
    short* wb_a1 = wb_aW + 131072;
    short* wb_a2 = wb_a1 + 131072;
    short* x_shb = wb_a2 + 131072;             // 2,621,440 (S,HN,B,H)
    short* wh2b  = x_shb + 2621440;            // 2,621,440
    float* out_sbd = (float*)(wh2b + 2621440); // 2,621,440 f32 (S,B,D)

    k_convert<<<dim3(640, 7), 256, 0, stream>>>(
        fc_w, q_w, k_w, v_w, attW, a1w, a2w,
        wb_fc, wb_q, wb_k, wb_v, wb_aW, wb_a1, wb_a2);
    k_target<<<dim3(16, HN_, S_), 256, 0, stream>>>(
        x, tgt, wb_fc, fc_b, wb_q, q_b, wb_a2, a2b, wb_aW, x_shb, wh2b);
    k_neighbor<<<dim3(256, HN_, S_), 256, 0, stream>>>(
        x, nbr, wb_fc, fc_b, wb_k, k_b, wb_v, v_b, wb_a1, a1b, x_shb, wh2b, out_sbd);
    k_semantic<<<dim3(B_), 256, 0, stream>>>(
        out_sbd, ip1w, ip1b, ip2w, bp1w, bp1b, bp2w, out);
}